// Round 12
// baseline (109.508 us; speedup 1.0000x reference)
//
#include <hip/hip_runtime.h>
#include <stdint.h>

// BCM_Linear: out = x @ W^T, W[o,k] = w[o>>6, k>>6, (o-k)&63]  (1024x1024)
// M=32768, N=1024, K=1024. bf16 MFMA compute, fp32 in/out.
// Round 12: R4 three-kernel pipeline (proven 111 us) with ONE change:
// GEMM K-loop upgraded from drain-VMCNT(0) to DISTANCE-2 counted VMCNT(4)
// (T3/T4 minimum form). Stage t+2 into the buffer just read (after
// lgkmcnt0+barrier), never drain to 0 in the main loop.

#define NTOK 32768
#define NCH  1024
#define NKT  16

typedef short bf16x8 __attribute__((ext_vector_type(8)));
typedef float f32x4  __attribute__((ext_vector_type(4)));
typedef unsigned short u16x8 __attribute__((ext_vector_type(8)));

static __device__ __forceinline__ unsigned short f2bf(float f) {
    unsigned int u = __float_as_uint(f);
    u += 0x7FFFu + ((u >> 16) & 1u);
    return (unsigned short)(u >> 16);
}

#define GLOAD16(gp, lp)                                                          \
    __builtin_amdgcn_global_load_lds(                                            \
        (const __attribute__((address_space(1))) unsigned int*)(gp),             \
        (__attribute__((address_space(3))) unsigned int*)(lp), 16, 0, 0)

// ---------------- kernel 1: x fp32 -> bf16, pre-swizzled (R2/R4 proven) ----------------
__global__ void cvt_x_kernel(const float* __restrict__ x, unsigned short* __restrict__ xb) {
    int i = blockIdx.x * blockDim.x + threadIdx.x;   // 0 .. NTOK*128-1
    int row = i >> 7;
    int j   = i & 127;
    const float4* src = (const float4*)(x + (((size_t)row) << 10) + (j << 3));
    float4 a = src[0], b = src[1];
    u16x8 v;
    v[0]=f2bf(a.x); v[1]=f2bf(a.y); v[2]=f2bf(a.z); v[3]=f2bf(a.w);
    v[4]=f2bf(b.x); v[5]=f2bf(b.y); v[6]=f2bf(b.z); v[7]=f2bf(b.w);
    int js = (j & ~7) | ((j & 7) ^ (row & 7));
    *(u16x8*)(xb + (((size_t)row) << 10) + (js << 3)) = v;
}

// ---------------- kernel 2: circulant w -> dense bf16 W, pre-swizzled (proven) ----------------
__global__ void build_w_kernel(const float* __restrict__ w, unsigned short* __restrict__ Wb) {
    int i = blockIdx.x * blockDim.x + threadIdx.x;   // 0 .. 1024*128-1
    int o = i >> 7;
    int j = i & 127;
    int r = o >> 6;
    int q = j >> 3;
    const float* wrow = w + ((r * 16 + q) << 6);
    int k0 = j << 3;
    u16x8 v;
#pragma unroll
    for (int e = 0; e < 8; ++e) v[e] = f2bf(wrow[(o - (k0 + e)) & 63]);
    int js = (j & ~7) | ((j & 7) ^ (o & 7));
    *(u16x8*)(Wb + (((size_t)o) << 10) + (js << 3)) = v;
}

// ---------------- kernel 3: 128x128 GEMM, distance-2 counted vmcnt ----------------
#define BAR() __builtin_amdgcn_s_barrier()
#define LGKM0() asm volatile("s_waitcnt lgkmcnt(0)" ::: "memory")
#define VMCNT(n) asm volatile("s_waitcnt vmcnt(" #n ")" ::: "memory")
#define SETPRIO(n) __builtin_amdgcn_s_setprio(n)
#define MFMA4(d, av, bv) d = __builtin_amdgcn_mfma_f32_16x16x32_bf16(av, bv, d, 0, 0, 0)
#define NOHOOK ((void)0)

// stage full 128x64 A-tile + 128x64 B-tile (16KB each): 4 gload16/thread (R4 verbatim).
#define STAGE(bufA, bufB, t) do {                                                \
    const char* _sa = srcA + ((t) << 7);                                         \
    const char* _sb = srcB + ((t) << 7);                                         \
    char* _da = (bufA) + (wv << 10);                                             \
    char* _db = (bufB) + (wv << 10);                                             \
    GLOAD16(_sa, _da); GLOAD16(_sa + (64 << 11), _da + 8192);                    \
    GLOAD16(_sb, _db); GLOAD16(_sb + (64 << 11), _db + 8192);                    \
} while (0)

// One K-tile, distance-2 schedule:
//   reads(t) ; lgkm0 ; BAR(all reads done) ; stage(t+2 -> same bufs) ;
//   MFMA ; VMCNT(4) [t+1 landed, t+2 in flight] ; BAR.
#define KSTEP2(Abuf, Bbuf, DO_STAGE, WN) do {                                    \
    bf16x8 afr[4][2], bfr[2][2];                                                 \
    _Pragma("unroll") for (int m = 0; m < 4; ++m)                                \
      _Pragma("unroll") for (int ks = 0; ks < 2; ++ks)                           \
        afr[m][ks] = *(const bf16x8*)((Abuf) + a_off[ks] + m * 2048);            \
    _Pragma("unroll") for (int n = 0; n < 2; ++n)                                \
      _Pragma("unroll") for (int ks = 0; ks < 2; ++ks)                           \
        bfr[n][ks] = *(const bf16x8*)((Bbuf) + b_off[ks] + n * 2048);            \
    LGKM0();                                                                     \
    BAR();                                                                       \
    DO_STAGE;                                                                    \
    SETPRIO(1);                                                                  \
    _Pragma("unroll") for (int m = 0; m < 4; ++m)                                \
      _Pragma("unroll") for (int n = 0; n < 2; ++n) {                            \
        MFMA4(acc[m][n], afr[m][0], bfr[n][0]);                                  \
        MFMA4(acc[m][n], afr[m][1], bfr[n][1]);                                  \
      }                                                                          \
    SETPRIO(0);                                                                  \
    WN;                                                                          \
    BAR();                                                                       \
} while (0)

__global__ void __launch_bounds__(512, 4) gemm128_kernel(const unsigned short* __restrict__ A,
                                                         const unsigned short* __restrict__ B,
                                                         float* __restrict__ C) {
    __shared__ __align__(16) char lds[65536];
    char* As0 = lds;                 // 128 rows x 128 B
    char* As1 = lds + 16384;
    char* Bs0 = lds + 32768;
    char* Bs1 = lds + 49152;

    int tid  = threadIdx.x;
    int lane = tid & 63;
    int wv   = tid >> 6;       // 0..7
    int wr   = wv >> 2;        // 0..1  (M: 2 x 64 rows)
    int wc   = wv & 3;         // 0..3  (N: 4 x 32 cols)

    // T1: XCD-chunked swizzle (R4 verbatim)
    int cpx = gridDim.x >> 3;
    int wid = ((int)blockIdx.x & 7) * cpx + ((int)blockIdx.x >> 3);
    int tn = wid & 7, tm = wid >> 3;
    int m0 = tm * 128, n0 = tn * 128;

    const char* srcA = (const char*)A + (((size_t)(m0 + (tid >> 3))) << 11) + ((tid & 7) << 4);
    const char* srcB = (const char*)B + (((size_t)(n0 + (tid >> 3))) << 11) + ((tid & 7) << 4);

    // T2 swizzled ds_read offsets (R4 verbatim)
    int xa   = (lane & 7) << 4;
    int kq16 = (lane >> 4) << 4;
    int abase = (wr * 64 + (lane & 15)) * 128;
    int bbase = (wc * 32 + (lane & 15)) * 128;
    int a_off[2] = { abase + (kq16 ^ xa), abase + ((64 + kq16) ^ xa) };
    int b_off[2] = { bbase + (kq16 ^ xa), bbase + ((64 + kq16) ^ xa) };

    f32x4 acc[4][2] = {};

    // ---- prologue: stage tiles 0 and 1; wait tile 0 only ----
    STAGE(As0, Bs0, 0);
    STAGE(As1, Bs1, 1);
    VMCNT(4); BAR();

    // ---- main loop: tiles 0..11 (stage t+2 / t+3) ----
    for (int t = 0; t < 12; t += 2) {
        KSTEP2(As0, Bs0, STAGE(As0, Bs0, t + 2), VMCNT(4));
        KSTEP2(As1, Bs1, STAGE(As1, Bs1, t + 3), VMCNT(4));
    }
    // ---- tiles 12, 13: stage 14, 15 ----
    KSTEP2(As0, Bs0, STAGE(As0, Bs0, 14), VMCNT(4));
    KSTEP2(As1, Bs1, STAGE(As1, Bs1, 15), VMCNT(4));
    // ---- tile 14: no stage, drain tile 15 ----
    KSTEP2(As0, Bs0, NOHOOK, VMCNT(0));
    // ---- tile 15: compute only ----
    {
        bf16x8 afr[4][2], bfr[2][2];
#pragma unroll
        for (int m = 0; m < 4; ++m)
#pragma unroll
            for (int ks = 0; ks < 2; ++ks)
                afr[m][ks] = *(const bf16x8*)(As1 + a_off[ks] + m * 2048);
#pragma unroll
        for (int n = 0; n < 2; ++n)
#pragma unroll
            for (int ks = 0; ks < 2; ++ks)
                bfr[n][ks] = *(const bf16x8*)(Bs1 + b_off[ks] + n * 2048);
        LGKM0();
        SETPRIO(1);
#pragma unroll
        for (int m = 0; m < 4; ++m)
#pragma unroll
            for (int n = 0; n < 2; ++n) {
                MFMA4(acc[m][n], afr[m][0], bfr[n][0]);
                MFMA4(acc[m][n], afr[m][1], bfr[n][1]);
            }
        SETPRIO(0);
    }

    // epilogue (R4 verbatim): C/D layout col = lane&15, row = (lane>>4)*4 + j
    float* Cp = C + ((size_t)(m0 + wr * 64)) * NCH + n0 + wc * 32;
    int cc = lane & 15;
    int rr = (lane >> 4) << 2;
#pragma unroll
    for (int m = 0; m < 4; ++m)
#pragma unroll
        for (int j = 0; j < 4; ++j) {
            float* rowp = Cp + ((size_t)(m * 16 + rr + j)) * NCH;
#pragma unroll
            for (int n = 0; n < 2; ++n)
                rowp[n * 16 + cc] = acc[m][n][j];
        }
}

// ---------------- fallback (ws too small): naive fp32 ----------------
__global__ void naive_kernel(const float* __restrict__ x, const float* __restrict__ w,
                             float* __restrict__ out) {
    int t = blockIdx.x;
    int o = blockIdx.y * 256 + threadIdx.x;
    const float* xr = x + (size_t)t * NCH;
    int r = o >> 6, oi = o & 63;
    float s = 0.f;
    for (int q = 0; q < 16; ++q) {
        const float* wq = w + (r * 16 + q) * 64;
        const float* xq = xr + q * 64;
#pragma unroll 8
        for (int j = 0; j < 64; ++j) s += xq[j] * wq[(oi - j) & 63];
    }
    out[(size_t)t * NCH + o] = s;
}

extern "C" void kernel_launch(void* const* d_in, const int* in_sizes, int n_in,
                              void* d_out, int out_size, void* d_ws, size_t ws_size,
                              hipStream_t stream) {
    const float* x = (const float*)d_in[0];
    const float* w = (const float*)d_in[1];
    float* out = (float*)d_out;

    const size_t needX = (size_t)NTOK * NCH * sizeof(unsigned short);  // 64 MB
    const size_t needW = (size_t)NCH * NCH * sizeof(unsigned short);   //  2 MB

    if (ws_size >= needX + needW) {
        unsigned short* xb = (unsigned short*)d_ws;
        unsigned short* Wb = (unsigned short*)((char*)d_ws + needX);
        hipLaunchKernelGGL(cvt_x_kernel, dim3(NTOK * 128 / 256), dim3(256), 0, stream, x, xb);
        hipLaunchKernelGGL(build_w_kernel, dim3(NCH * 128 / 256), dim3(256), 0, stream, w, Wb);
        hipLaunchKernelGGL(gemm128_kernel, dim3(2048), dim3(512), 0, stream, xb, Wb, out);
    } else {
        hipLaunchKernelGGL(naive_kernel, dim3(NTOK, 4), dim3(256), 0, stream, x, w, out);
    }
}